// Round 4
// baseline (450.149 us; speedup 1.0000x reference)
//
#include <hip/hip_runtime.h>

typedef unsigned int uint;
typedef unsigned short ushort;

using bf16x8 = __attribute__((ext_vector_type(8))) short;
using f32x4  = __attribute__((ext_vector_type(4))) float;

__device__ __forceinline__ float lrelu(float v) { return v > 0.f ? v : 0.01f * v; }
__device__ __forceinline__ float b2f(ushort u) { return __uint_as_float((uint)u << 16); }
__device__ __forceinline__ ushort f2b(float f) {
  uint u = __float_as_uint(f);
  u += 0x7fffu + ((u >> 16) & 1u);   // round-to-nearest-even
  return (ushort)(u >> 16);
}

#define CSR_B 256          // blocks in coarse passes
#define BKT_SHIFT 10       // 1024 dst nodes per bucket
#define MAX_NB 64          // max buckets (N <= 65536)

// y buffers are CHANNEL-CHUNKED: y[chunk][node][16], chunk = ch>>4 (8 chunks).
// Each chunk is a contiguous N*32 B region -> one 1.6 MB slab per XCD's L2.

// ---------------------------------------------------------------------------
// MFMA GEMM: C[N,128] = A[N,K] @ W[K,128] + bias, bf16 in / fp32 acc.
// A given as up to 4 chunked y-buffer pointers (K = 128*chunks).
// Wt pre-transposed: Wt[n][k] bf16.
// MODE 0: h = lrelu(acc+b); yout = bf16(lrelu(h))           (readin)
// MODE 1: h += acc+b; if yout: yout = bf16(act? lrelu(h):h) (layer taps, fused cast)
// MODE 2: h = acc+b                                          (readout)
// ---------------------------------------------------------------------------
template <int MODE, int K>
__global__ __launch_bounds__(256) void gemm_mfma(
    const ushort* __restrict__ A0, const ushort* __restrict__ A1,
    const ushort* __restrict__ A2, const ushort* __restrict__ A3,
    const ushort* __restrict__ Wt, const float* __restrict__ bias,
    float* __restrict__ h, ushort* __restrict__ yout, int do_act, int N) {
  __shared__ ushort As[64][40];    // [m][k], stride 40 (16B-aligned, 2-way-free banks)
  __shared__ ushort Bs[128][40];   // [n][k]
  const int tid = threadIdx.x;
  const int lane = tid & 63;
  const int wave = tid >> 6;
  const int g = lane >> 4;         // k-quad
  const int mr = lane & 15;
  const int wr = wave >> 1;        // row half
  const int wc = wave & 1;         // col half
  const int row0 = blockIdx.x * 64;

  const ushort* Ap[4] = {A0, A1, A2, A3};

  f32x4 acc[2][4];
#pragma unroll
  for (int i = 0; i < 2; i++)
#pragma unroll
    for (int j = 0; j < 4; j++) acc[i][j] = (f32x4){0.f, 0.f, 0.f, 0.f};

#pragma unroll 4
  for (int kc = 0; kc < K; kc += 32) {
    {  // stage A: 64 rows x 32 k (one uint4 per thread), chunked layout
      int m = tid >> 2, q = tid & 3;
      int r = row0 + m;
      if (r >= N) r = N - 1;
      int kg = kc + q * 8;
      const ushort* ap = Ap[kg >> 7] + ((size_t)((kg >> 4) & 7)) * N * 16 +
                         (size_t)r * 16 + (kg & 15);
      *(uint4*)&As[m][q * 8] = *(const uint4*)ap;
    }
#pragma unroll
    for (int t = 0; t < 2; t++) {  // stage B: 128 n x 32 k
      int slot = tid + t * 256;
      int n = slot >> 2, q = slot & 3;
      *(uint4*)&Bs[n][q * 8] = *(const uint4*)(Wt + (size_t)n * K + kc + q * 8);
    }
    __syncthreads();
    bf16x8 af[2], bf[4];
#pragma unroll
    for (int rt = 0; rt < 2; rt++) af[rt] = *(bf16x8*)&As[wr * 32 + rt * 16 + mr][g * 8];
#pragma unroll
    for (int ct = 0; ct < 4; ct++) bf[ct] = *(bf16x8*)&Bs[wc * 64 + ct * 16 + mr][g * 8];
#pragma unroll
    for (int rt = 0; rt < 2; rt++)
#pragma unroll
      for (int ct = 0; ct < 4; ct++)
        acc[rt][ct] = __builtin_amdgcn_mfma_f32_16x16x32_bf16(af[rt], bf[ct], acc[rt][ct], 0, 0, 0);
    __syncthreads();
  }

  // epilogue: C/D layout col=lane&15, row=(lane>>4)*4+reg
#pragma unroll
  for (int rt = 0; rt < 2; rt++) {
#pragma unroll
    for (int i = 0; i < 4; i++) {
      int R = row0 + wr * 32 + rt * 16 + g * 4 + i;
      if (R >= N) continue;
#pragma unroll
      for (int ct = 0; ct < 4; ct++) {
        int c = wc * 64 + ct * 16 + mr;       // c&15 == mr, c>>4 == wc*4+ct
        float v = acc[rt][ct][i] + bias[c];
        size_t o = (size_t)R * 128 + c;
        size_t oy = (size_t)(wc * 4 + ct) * N * 16 + (size_t)R * 16 + mr;
        if (MODE == 0) {
          float hv = lrelu(v);
          h[o] = hv;
          yout[oy] = f2b(lrelu(hv));
        } else if (MODE == 1) {
          float hv = h[o] + v;
          h[o] = hv;
          if (yout) yout[oy] = f2b(do_act ? lrelu(hv) : hv);
        } else {
          h[o] = v;
        }
      }
    }
  }
}

// ---------------- bf16 aggregation, chunked: out[c][n] = sum y[c][src] -------
// chunk = blockIdx&7 -> one chunk per XCD (round-robin heuristic): gather
// working set = 1.6 MB y-chunk + esrc slice -> L2-resident.
// 4 lanes x uint2 (4 bf16) per node, 64 nodes per block, 4-way unrolled.
__global__ __launch_bounds__(256) void agg_bf16(const ushort* __restrict__ yin,
                                                ushort* __restrict__ yout,
                                                const int* __restrict__ rowp,
                                                const ushort* __restrict__ esrc, int N) {
  int t = threadIdx.x;
  int chunk = blockIdx.x & 7;
  int node = (blockIdx.x >> 3) * 64 + (t >> 2);
  if (node >= N) return;
  int lane = t & 3;
  const ushort* yb = yin + (size_t)chunk * N * 16 + lane * 4;
  int beg = rowp[node], end = rowp[node + 1];
  float s[4] = {0.f, 0.f, 0.f, 0.f};
  int j = beg;
  for (; j + 4 <= end; j += 4) {
    int s0 = esrc[j], s1 = esrc[j + 1], s2 = esrc[j + 2], s3 = esrc[j + 3];
    union { uint2 v; ushort u[4]; } w0, w1, w2, w3;
    w0.v = *(const uint2*)(yb + (size_t)s0 * 16);
    w1.v = *(const uint2*)(yb + (size_t)s1 * 16);
    w2.v = *(const uint2*)(yb + (size_t)s2 * 16);
    w3.v = *(const uint2*)(yb + (size_t)s3 * 16);
#pragma unroll
    for (int e = 0; e < 4; e++)
      s[e] += (b2f(w0.u[e]) + b2f(w1.u[e])) + (b2f(w2.u[e]) + b2f(w3.u[e]));
  }
  for (; j < end; j++) {
    int sn = esrc[j];
    union { uint2 v; ushort u[4]; } w;
    w.v = *(const uint2*)(yb + (size_t)sn * 16);
#pragma unroll
    for (int e = 0; e < 4; e++) s[e] += b2f(w.u[e]);
  }
  union { uint2 v; ushort u[4]; } o;
#pragma unroll
  for (int e = 0; e < 4; e++) o.u[e] = f2b(s[e]);
  *(uint2*)(yout + (size_t)chunk * N * 16 + (size_t)node * 16 + lane * 4) = o.v;
}

// ---------------- fp32 [N][128] -> bf16 chunked y ----------------
__global__ __launch_bounds__(256) void cast_f2b(const float* __restrict__ in,
                                                ushort* __restrict__ out, int N) {
  int i = blockIdx.x * 256 + threadIdx.x;
  if (i >= N * 16) return;
  int node = i >> 4, sub = i & 15;           // 8 channels per thread
  float4 a = *(const float4*)(in + (size_t)node * 128 + sub * 8);
  float4 b = *(const float4*)(in + (size_t)node * 128 + sub * 8 + 4);
  float v[8] = {a.x, a.y, a.z, a.w, b.x, b.y, b.z, b.w};
  union { uint4 q; ushort u[8]; } o;
#pragma unroll
  for (int e = 0; e < 8; e++) o.u[e] = f2b(v[e]);
  int chunk = sub >> 1, off = (sub & 1) * 8;
  *(uint4*)(out + (size_t)chunk * N * 16 + (size_t)node * 16 + off) = o.q;
}

// ---------------- weight prep: cast + transpose + bias sums ------------------
__global__ __launch_bounds__(256) void prep_k(const float* __restrict__ w_in,
                                              const float* __restrict__ w_out,
                                              const float* __restrict__ taps_w,
                                              const float* __restrict__ taps_b,
                                              ushort* __restrict__ Wt_in,
                                              ushort* __restrict__ Wt_out,
                                              ushort* __restrict__ Wt_l0,
                                              ushort* __restrict__ Wt_l1,
                                              float* __restrict__ bsum) {
  int gid = blockIdx.x * 256 + threadIdx.x;
  if (gid < 16384) {
    int n = gid >> 7, k = gid & 127;
    Wt_in[gid] = f2b(w_in[k * 128 + n]);
  } else if (gid < 32768) {
    int i = gid - 16384;
    int n = i >> 7, k = i & 127;
    Wt_out[i] = f2b(w_out[k * 128 + n]);
  } else if (gid < 98304) {
    int i = gid - 32768;
    int n = i >> 9, k = i & 511;
    Wt_l0[i] = f2b(taps_w[(size_t)k * 128 + n]);
  } else if (gid < 163840) {
    int i = gid - 98304;
    int n = i >> 9, k = i & 511;
    Wt_l1[i] = f2b(taps_w[(size_t)(512 + k) * 128 + n]);
  } else if (gid < 164096) {
    int i = gid - 163840;
    int l = i >> 7, n = i & 127;
    float s = 0.f;
    for (int k = 0; k < 4; k++) s += taps_b[l * 512 + k * 128 + n];
    bsum[i] = s;
  }
}

// ---------------- CSR build: 2-level binned counting sort --------------------
__global__ __launch_bounds__(256) void chist_k(const int* __restrict__ dst,
                                               int* __restrict__ H, int E, int NB) {
  __shared__ int hh[MAX_NB];
  if (threadIdx.x < NB) hh[threadIdx.x] = 0;
  __syncthreads();
  int chunk = (E + gridDim.x - 1) / gridDim.x;
  int beg = blockIdx.x * chunk, end = min(E, beg + chunk);
  for (int e = beg + threadIdx.x; e < end; e += 256)
    atomicAdd(&hh[dst[e] >> BKT_SHIFT], 1);
  __syncthreads();
  if (threadIdx.x < NB) H[threadIdx.x * gridDim.x + blockIdx.x] = hh[threadIdx.x];
}

__global__ __launch_bounds__(256) void cscan_k(int* __restrict__ H, int M) {
  __shared__ int sm[256];
  int per = (M + 255) / 256;
  int b0 = threadIdx.x * per;
  int hi = min(M, b0 + per);
  int sum = 0;
  for (int i = b0; i < hi; i++) sum += H[i];
  sm[threadIdx.x] = sum;
  __syncthreads();
  int x = sum;
  for (int off = 1; off < 256; off <<= 1) {
    int tt = (threadIdx.x >= off) ? sm[threadIdx.x - off] : 0;
    __syncthreads();
    x += tt;
    sm[threadIdx.x] = x;
    __syncthreads();
  }
  int run = x - sum;  // exclusive
  for (int i = b0; i < hi; i++) {
    int v = H[i];
    H[i] = run;
    run += v;
  }
}

__global__ __launch_bounds__(256) void cscatter_k(const int* __restrict__ src,
                                                  const int* __restrict__ dst,
                                                  const int* __restrict__ H,
                                                  uint* __restrict__ packed,
                                                  int E, int NB) {
  __shared__ int cur[MAX_NB];
  int chunk = (E + gridDim.x - 1) / gridDim.x;
  int beg = blockIdx.x * chunk, end = min(E, beg + chunk);
  if (threadIdx.x < NB) cur[threadIdx.x] = H[threadIdx.x * gridDim.x + blockIdx.x];
  __syncthreads();
  for (int e = beg + threadIdx.x; e < end; e += 256) {
    int d = dst[e];
    int pos = atomicAdd(&cur[d >> BKT_SHIFT], 1);
    packed[pos] = ((uint)d << 16) | (uint)src[e];
  }
}

__global__ __launch_bounds__(256) void fsort_k(const uint* __restrict__ packed,
                                               const int* __restrict__ H,
                                               ushort* __restrict__ esrc,
                                               int* __restrict__ rowp,
                                               int N, int E, int NB) {
  __shared__ int hist[1 << BKT_SHIFT];
  __shared__ int cur[1 << BKT_SHIFT];
  __shared__ int sm[256];
  const int bkt = blockIdx.x;
  const int base = bkt << BKT_SHIFT;
  const int nb_nodes = min(1 << BKT_SHIFT, N - base);
  const int start = H[bkt * CSR_B];
  const int end = (bkt == NB - 1) ? E : H[(bkt + 1) * CSR_B];

  for (int i = threadIdx.x; i < (1 << BKT_SHIFT); i += 256) hist[i] = 0;
  __syncthreads();
  for (int e = start + threadIdx.x; e < end; e += 256)
    atomicAdd(&hist[(packed[e] >> 16) - base], 1);
  __syncthreads();

  int t4 = threadIdx.x * 4;
  int l0 = hist[t4], l1 = hist[t4 + 1], l2 = hist[t4 + 2], l3 = hist[t4 + 3];
  int ssum = l0 + l1 + l2 + l3;
  sm[threadIdx.x] = ssum;
  __syncthreads();
  int x = ssum;
  for (int off = 1; off < 256; off <<= 1) {
    int tt = (threadIdx.x >= off) ? sm[threadIdx.x - off] : 0;
    __syncthreads();
    x += tt;
    sm[threadIdx.x] = x;
    __syncthreads();
  }
  int c0 = start + x - ssum;
  int c1 = c0 + l0, c2 = c1 + l1, c3 = c2 + l2;
  cur[t4] = c0; cur[t4 + 1] = c1; cur[t4 + 2] = c2; cur[t4 + 3] = c3;
  if (t4 + 0 < nb_nodes) rowp[base + t4 + 0] = c0;
  if (t4 + 1 < nb_nodes) rowp[base + t4 + 1] = c1;
  if (t4 + 2 < nb_nodes) rowp[base + t4 + 2] = c2;
  if (t4 + 3 < nb_nodes) rowp[base + t4 + 3] = c3;
  __syncthreads();

  for (int e = start + threadIdx.x; e < end; e += 256) {
    uint p = packed[e];
    int pos = atomicAdd(&cur[(p >> 16) - base], 1);
    esrc[pos] = (ushort)(p & 0xffffu);
  }
  if (bkt == 0 && threadIdx.x == 0) rowp[N] = E;
}

// ---------------------------------------------------------------------------
extern "C" void kernel_launch(void* const* d_in, const int* in_sizes, int n_in,
                              void* d_out, int out_size, void* d_ws, size_t ws_size,
                              hipStream_t stream) {
  const float* x      = (const float*)d_in[0];
  const int*   ei     = (const int*)d_in[1];
  const float* w_in   = (const float*)d_in[2];
  const float* b_in   = (const float*)d_in[3];
  const float* taps_w = (const float*)d_in[4];
  const float* taps_b = (const float*)d_in[5];
  const float* w_out  = (const float*)d_in[6];
  const float* b_out  = (const float*)d_in[7];

  const int N = in_sizes[0] / 128;
  const int E = in_sizes[1] / 2;
  const int* src = ei;
  const int* dst = ei + E;
  const int NB = (N + (1 << BKT_SHIFT) - 1) >> BKT_SHIFT;

  // h (fp32) lives in d_out until the readout GEMM overwrites it.
  float* h = (float*)d_out;

  // workspace (~57 MB)
  const size_t yelem = (size_t)N * 128;
  ushort* y0 = (ushort*)d_ws;
  ushort* y1 = y0 + yelem;
  ushort* y2 = y1 + yelem;
  ushort* y3 = y2 + yelem;
  ushort* Wt_in  = y3 + yelem;             // 128*128
  ushort* Wt_out = Wt_in + 128 * 128;      // 128*128
  ushort* Wt_l0  = Wt_out + 128 * 128;     // 128*512
  ushort* Wt_l1  = Wt_l0 + 128 * 512;      // 128*512
  float*  bsum   = (float*)(Wt_l1 + 128 * 512);   // 256
  int*    rowp   = (int*)(bsum + 256);     // N+1
  int*    H      = rowp + (N + 1);         // NB*CSR_B
  uint*   packed = (uint*)(H + MAX_NB * CSR_B);   // E
  ushort* esrc   = (ushort*)(packed + E);  // E

  const int gemmB = (N + 63) / 64;
  const int aggB  = ((N + 63) / 64) * 8;   // node-blocks x 8 chunks
  const int castB = (N * 16 + 255) / 256;

  // ---- CSR build (binned counting sort) ----
  chist_k<<<CSR_B, 256, 0, stream>>>(dst, H, E, NB);
  cscan_k<<<1, 256, 0, stream>>>(H, NB * CSR_B);
  cscatter_k<<<CSR_B, 256, 0, stream>>>(src, dst, H, packed, E, NB);
  fsort_k<<<NB, 256, 0, stream>>>(packed, H, esrc, rowp, N, E, NB);

  // ---- weight prep + x cast (chunked) ----
  prep_k<<<641, 256, 0, stream>>>(w_in, w_out, taps_w, taps_b,
                                  Wt_in, Wt_out, Wt_l0, Wt_l1, bsum);
  cast_f2b<<<castB, 256, 0, stream>>>(x, y1, N);

  // ---- readin: h = lrelu(x@Win+b); y0 = bf16(lrelu(h)) ----
  gemm_mfma<0, 128><<<gemmB, 256, 0, stream>>>(y1, y1, y1, y1, Wt_in, b_in, h, y0, 0, N);

  // ---- 2 residual graph-filter layers (cast fused into GEMM epilogue) ----
  for (int l = 0; l < 2; l++) {
    const ushort* Wt_l = (l == 0) ? Wt_l0 : Wt_l1;
    agg_bf16<<<aggB, 256, 0, stream>>>(y0, y1, rowp, esrc, N);
    agg_bf16<<<aggB, 256, 0, stream>>>(y1, y2, rowp, esrc, N);
    agg_bf16<<<aggB, 256, 0, stream>>>(y2, y3, rowp, esrc, N);
    gemm_mfma<1, 512><<<gemmB, 256, 0, stream>>>(y0, y1, y2, y3, Wt_l, bsum + l * 128,
                                                 h, y0, (l == 0) ? 1 : 0, N);
  }

  // ---- readout: d_out = h @ Wout + bout (reads y0 = bf16(h)) ----
  gemm_mfma<2, 128><<<gemmB, 256, 0, stream>>>(y0, y0, y0, y0, Wt_out, b_out,
                                               (float*)d_out, nullptr, 0, N);
}

// Round 5
// 391.772 us; speedup vs baseline: 1.1490x; 1.1490x over previous
//
#include <hip/hip_runtime.h>

typedef unsigned int uint;
typedef unsigned short ushort;

using bf16x8 = __attribute__((ext_vector_type(8))) short;
using f32x4  = __attribute__((ext_vector_type(4))) float;

__device__ __forceinline__ float lrelu(float v) { return v > 0.f ? v : 0.01f * v; }
__device__ __forceinline__ float b2f(ushort u) { return __uint_as_float((uint)u << 16); }
__device__ __forceinline__ ushort f2b(float f) {
  uint u = __float_as_uint(f);
  u += 0x7fffu + ((u >> 16) & 1u);   // round-to-nearest-even
  return (ushort)(u >> 16);
}

#define CSR_B 256          // blocks in coarse passes
#define BKT_SHIFT 10       // 1024 dst nodes per bucket
#define MAX_NB 64          // max buckets (N <= 65536)

// y buffers are CHANNEL-CHUNKED into 4 chunks of 32 ch: y[chunk][node][32].
// Row = 64 B = exactly one cache line (no partial-line waste on random gather);
// chunk slab = N*64 B = 3.2 MB < 4 MiB per-XCD L2. agg uses chunk=blockIdx&3 so
// with round-robin block->XCD dispatch each XCD's L2 holds exactly one chunk.

// ---------------------------------------------------------------------------
// MFMA GEMM: C[N,128] = A[N,K] @ W[K,128] + bias, bf16 in / fp32 acc.
// A given as up to 4 chunked y-buffer pointers (K = 128*chunks).
// Wt pre-transposed: Wt[n][k] bf16.
// MODE 0: h = lrelu(acc+b); yout = bf16(lrelu(h))           (readin)
// MODE 1: h += acc+b; if yout: yout = bf16(act? lrelu(h):h) (layer taps, fused cast)
// MODE 2: h = acc+b                                          (readout)
// ---------------------------------------------------------------------------
template <int MODE, int K>
__global__ __launch_bounds__(256) void gemm_mfma(
    const ushort* __restrict__ A0, const ushort* __restrict__ A1,
    const ushort* __restrict__ A2, const ushort* __restrict__ A3,
    const ushort* __restrict__ Wt, const float* __restrict__ bias,
    float* __restrict__ h, ushort* __restrict__ yout, int do_act, int N) {
  __shared__ ushort As[64][40];    // [m][k], stride 40 (16B-aligned, 2-way-free banks)
  __shared__ ushort Bs[128][40];   // [n][k]
  const int tid = threadIdx.x;
  const int lane = tid & 63;
  const int wave = tid >> 6;
  const int g = lane >> 4;         // k-quad
  const int mr = lane & 15;
  const int wr = wave >> 1;        // row half
  const int wc = wave & 1;         // col half
  const int row0 = blockIdx.x * 64;

  const ushort* Ap[4] = {A0, A1, A2, A3};

  f32x4 acc[2][4];
#pragma unroll
  for (int i = 0; i < 2; i++)
#pragma unroll
    for (int j = 0; j < 4; j++) acc[i][j] = (f32x4){0.f, 0.f, 0.f, 0.f};

#pragma unroll 4
  for (int kc = 0; kc < K; kc += 32) {
    {  // stage A: 64 rows x 32 k (one uint4 per thread), 4x32-chunked layout
      int m = tid >> 2, q = tid & 3;
      int r = row0 + m;
      if (r >= N) r = N - 1;
      int kg = kc + q * 8;
      const ushort* ap = Ap[kg >> 7] + ((size_t)((kg >> 5) & 3)) * N * 32 +
                         (size_t)r * 32 + (kg & 31);
      *(uint4*)&As[m][q * 8] = *(const uint4*)ap;
    }
#pragma unroll
    for (int t = 0; t < 2; t++) {  // stage B: 128 n x 32 k
      int slot = tid + t * 256;
      int n = slot >> 2, q = slot & 3;
      *(uint4*)&Bs[n][q * 8] = *(const uint4*)(Wt + (size_t)n * K + kc + q * 8);
    }
    __syncthreads();
    bf16x8 af[2], bf[4];
#pragma unroll
    for (int rt = 0; rt < 2; rt++) af[rt] = *(bf16x8*)&As[wr * 32 + rt * 16 + mr][g * 8];
#pragma unroll
    for (int ct = 0; ct < 4; ct++) bf[ct] = *(bf16x8*)&Bs[wc * 64 + ct * 16 + mr][g * 8];
#pragma unroll
    for (int rt = 0; rt < 2; rt++)
#pragma unroll
      for (int ct = 0; ct < 4; ct++)
        acc[rt][ct] = __builtin_amdgcn_mfma_f32_16x16x32_bf16(af[rt], bf[ct], acc[rt][ct], 0, 0, 0);
    __syncthreads();
  }

  // epilogue: C/D layout col=lane&15, row=(lane>>4)*4+reg
#pragma unroll
  for (int rt = 0; rt < 2; rt++) {
#pragma unroll
    for (int i = 0; i < 4; i++) {
      int R = row0 + wr * 32 + rt * 16 + g * 4 + i;
      if (R >= N) continue;
#pragma unroll
      for (int ct = 0; ct < 4; ct++) {
        int c = wc * 64 + ct * 16 + mr;       // chunk = c>>5, within = c&31
        float v = acc[rt][ct][i] + bias[c];
        size_t o = (size_t)R * 128 + c;
        size_t oy = (size_t)(c >> 5) * N * 32 + (size_t)R * 32 + (c & 31);
        if (MODE == 0) {
          float hv = lrelu(v);
          h[o] = hv;
          yout[oy] = f2b(lrelu(hv));
        } else if (MODE == 1) {
          float hv = h[o] + v;
          h[o] = hv;
          if (yout) yout[oy] = f2b(do_act ? lrelu(hv) : hv);
        } else {
          h[o] = v;
        }
      }
    }
  }
}

// ---------------- bf16 aggregation, chunked: out[c][n] = sum y[c][src] -------
// chunk = blockIdx&3 -> one chunk per XCD pair under round-robin dispatch.
// 4 lanes x uint4 (8 bf16 = 16 B) per node -> one 64 B line per lane-quad.
// 64 nodes per block, 4-way unrolled gather.
__global__ __launch_bounds__(256) void agg_bf16(const ushort* __restrict__ yin,
                                                ushort* __restrict__ yout,
                                                const int* __restrict__ rowp,
                                                const ushort* __restrict__ esrc, int N) {
  int t = threadIdx.x;
  int chunk = blockIdx.x & 3;
  int node = (blockIdx.x >> 2) * 64 + (t >> 2);
  if (node >= N) return;
  int lane = t & 3;
  const ushort* yb = yin + (size_t)chunk * N * 32 + lane * 8;
  int beg = rowp[node], end = rowp[node + 1];
  float s[8] = {0.f, 0.f, 0.f, 0.f, 0.f, 0.f, 0.f, 0.f};
  int j = beg;
  for (; j + 4 <= end; j += 4) {
    int s0 = esrc[j], s1 = esrc[j + 1], s2 = esrc[j + 2], s3 = esrc[j + 3];
    union { uint4 v; ushort u[8]; } w0, w1, w2, w3;
    w0.v = *(const uint4*)(yb + (size_t)s0 * 32);
    w1.v = *(const uint4*)(yb + (size_t)s1 * 32);
    w2.v = *(const uint4*)(yb + (size_t)s2 * 32);
    w3.v = *(const uint4*)(yb + (size_t)s3 * 32);
#pragma unroll
    for (int e = 0; e < 8; e++)
      s[e] += (b2f(w0.u[e]) + b2f(w1.u[e])) + (b2f(w2.u[e]) + b2f(w3.u[e]));
  }
  for (; j < end; j++) {
    int sn = esrc[j];
    union { uint4 v; ushort u[8]; } w;
    w.v = *(const uint4*)(yb + (size_t)sn * 32);
#pragma unroll
    for (int e = 0; e < 8; e++) s[e] += b2f(w.u[e]);
  }
  union { uint4 v; ushort u[8]; } o;
#pragma unroll
  for (int e = 0; e < 8; e++) o.u[e] = f2b(s[e]);
  *(uint4*)(yout + (size_t)chunk * N * 32 + (size_t)node * 32 + lane * 8) = o.v;
}

// ---------------- fp32 [N][128] -> bf16 chunked y ----------------
__global__ __launch_bounds__(256) void cast_f2b(const float* __restrict__ in,
                                                ushort* __restrict__ out, int N) {
  int i = blockIdx.x * 256 + threadIdx.x;
  if (i >= N * 16) return;
  int node = i >> 4, sub = i & 15;           // 8 channels per thread
  float4 a = *(const float4*)(in + (size_t)node * 128 + sub * 8);
  float4 b = *(const float4*)(in + (size_t)node * 128 + sub * 8 + 4);
  float v[8] = {a.x, a.y, a.z, a.w, b.x, b.y, b.z, b.w};
  union { uint4 q; ushort u[8]; } o;
#pragma unroll
  for (int e = 0; e < 8; e++) o.u[e] = f2b(v[e]);
  int chunk = sub >> 2, off = (sub & 3) * 8;
  *(uint4*)(out + (size_t)chunk * N * 32 + (size_t)node * 32 + off) = o.q;
}

// ---------------- weight prep: cast + transpose + bias sums ------------------
__global__ __launch_bounds__(256) void prep_k(const float* __restrict__ w_in,
                                              const float* __restrict__ w_out,
                                              const float* __restrict__ taps_w,
                                              const float* __restrict__ taps_b,
                                              ushort* __restrict__ Wt_in,
                                              ushort* __restrict__ Wt_out,
                                              ushort* __restrict__ Wt_l0,
                                              ushort* __restrict__ Wt_l1,
                                              float* __restrict__ bsum) {
  int gid = blockIdx.x * 256 + threadIdx.x;
  if (gid < 16384) {
    int n = gid >> 7, k = gid & 127;
    Wt_in[gid] = f2b(w_in[k * 128 + n]);
  } else if (gid < 32768) {
    int i = gid - 16384;
    int n = i >> 7, k = i & 127;
    Wt_out[i] = f2b(w_out[k * 128 + n]);
  } else if (gid < 98304) {
    int i = gid - 32768;
    int n = i >> 9, k = i & 511;
    Wt_l0[i] = f2b(taps_w[(size_t)k * 128 + n]);
  } else if (gid < 163840) {
    int i = gid - 98304;
    int n = i >> 9, k = i & 511;
    Wt_l1[i] = f2b(taps_w[(size_t)(512 + k) * 128 + n]);
  } else if (gid < 164096) {
    int i = gid - 163840;
    int l = i >> 7, n = i & 127;
    float s = 0.f;
    for (int k = 0; k < 4; k++) s += taps_b[l * 512 + k * 128 + n];
    bsum[i] = s;
  }
}

// ---------------- CSR build: 2-level binned counting sort --------------------
__global__ __launch_bounds__(256) void chist_k(const int* __restrict__ dst,
                                               int* __restrict__ H, int E, int NB) {
  __shared__ int hh[MAX_NB];
  if (threadIdx.x < NB) hh[threadIdx.x] = 0;
  __syncthreads();
  int chunk = (E + gridDim.x - 1) / gridDim.x;
  int beg = blockIdx.x * chunk, end = min(E, beg + chunk);
  for (int e = beg + threadIdx.x; e < end; e += 256)
    atomicAdd(&hh[dst[e] >> BKT_SHIFT], 1);
  __syncthreads();
  if (threadIdx.x < NB) H[threadIdx.x * gridDim.x + blockIdx.x] = hh[threadIdx.x];
}

__global__ __launch_bounds__(256) void cscan_k(int* __restrict__ H, int M) {
  __shared__ int sm[256];
  int per = (M + 255) / 256;
  int b0 = threadIdx.x * per;
  int hi = min(M, b0 + per);
  int sum = 0;
  for (int i = b0; i < hi; i++) sum += H[i];
  sm[threadIdx.x] = sum;
  __syncthreads();
  int x = sum;
  for (int off = 1; off < 256; off <<= 1) {
    int tt = (threadIdx.x >= off) ? sm[threadIdx.x - off] : 0;
    __syncthreads();
    x += tt;
    sm[threadIdx.x] = x;
    __syncthreads();
  }
  int run = x - sum;  // exclusive
  for (int i = b0; i < hi; i++) {
    int v = H[i];
    H[i] = run;
    run += v;
  }
}

__global__ __launch_bounds__(256) void cscatter_k(const int* __restrict__ src,
                                                  const int* __restrict__ dst,
                                                  const int* __restrict__ H,
                                                  uint* __restrict__ packed,
                                                  int E, int NB) {
  __shared__ int cur[MAX_NB];
  int chunk = (E + gridDim.x - 1) / gridDim.x;
  int beg = blockIdx.x * chunk, end = min(E, beg + chunk);
  if (threadIdx.x < NB) cur[threadIdx.x] = H[threadIdx.x * gridDim.x + blockIdx.x];
  __syncthreads();
  for (int e = beg + threadIdx.x; e < end; e += 256) {
    int d = dst[e];
    int pos = atomicAdd(&cur[d >> BKT_SHIFT], 1);
    packed[pos] = ((uint)d << 16) | (uint)src[e];
  }
}

__global__ __launch_bounds__(256) void fsort_k(const uint* __restrict__ packed,
                                               const int* __restrict__ H,
                                               ushort* __restrict__ esrc,
                                               int* __restrict__ rowp,
                                               int N, int E, int NB) {
  __shared__ int hist[1 << BKT_SHIFT];
  __shared__ int cur[1 << BKT_SHIFT];
  __shared__ int sm[256];
  const int bkt = blockIdx.x;
  const int base = bkt << BKT_SHIFT;
  const int nb_nodes = min(1 << BKT_SHIFT, N - base);
  const int start = H[bkt * CSR_B];
  const int end = (bkt == NB - 1) ? E : H[(bkt + 1) * CSR_B];

  for (int i = threadIdx.x; i < (1 << BKT_SHIFT); i += 256) hist[i] = 0;
  __syncthreads();
  for (int e = start + threadIdx.x; e < end; e += 256)
    atomicAdd(&hist[(packed[e] >> 16) - base], 1);
  __syncthreads();

  int t4 = threadIdx.x * 4;
  int l0 = hist[t4], l1 = hist[t4 + 1], l2 = hist[t4 + 2], l3 = hist[t4 + 3];
  int ssum = l0 + l1 + l2 + l3;
  sm[threadIdx.x] = ssum;
  __syncthreads();
  int x = ssum;
  for (int off = 1; off < 256; off <<= 1) {
    int tt = (threadIdx.x >= off) ? sm[threadIdx.x - off] : 0;
    __syncthreads();
    x += tt;
    sm[threadIdx.x] = x;
    __syncthreads();
  }
  int c0 = start + x - ssum;
  int c1 = c0 + l0, c2 = c1 + l1, c3 = c2 + l2;
  cur[t4] = c0; cur[t4 + 1] = c1; cur[t4 + 2] = c2; cur[t4 + 3] = c3;
  if (t4 + 0 < nb_nodes) rowp[base + t4 + 0] = c0;
  if (t4 + 1 < nb_nodes) rowp[base + t4 + 1] = c1;
  if (t4 + 2 < nb_nodes) rowp[base + t4 + 2] = c2;
  if (t4 + 3 < nb_nodes) rowp[base + t4 + 3] = c3;
  __syncthreads();

  for (int e = start + threadIdx.x; e < end; e += 256) {
    uint p = packed[e];
    int pos = atomicAdd(&cur[(p >> 16) - base], 1);
    esrc[pos] = (ushort)(p & 0xffffu);
  }
  if (bkt == 0 && threadIdx.x == 0) rowp[N] = E;
}

// ---------------------------------------------------------------------------
extern "C" void kernel_launch(void* const* d_in, const int* in_sizes, int n_in,
                              void* d_out, int out_size, void* d_ws, size_t ws_size,
                              hipStream_t stream) {
  const float* x      = (const float*)d_in[0];
  const int*   ei     = (const int*)d_in[1];
  const float* w_in   = (const float*)d_in[2];
  const float* b_in   = (const float*)d_in[3];
  const float* taps_w = (const float*)d_in[4];
  const float* taps_b = (const float*)d_in[5];
  const float* w_out  = (const float*)d_in[6];
  const float* b_out  = (const float*)d_in[7];

  const int N = in_sizes[0] / 128;
  const int E = in_sizes[1] / 2;
  const int* src = ei;
  const int* dst = ei + E;
  const int NB = (N + (1 << BKT_SHIFT) - 1) >> BKT_SHIFT;

  // h (fp32) lives in d_out until the readout GEMM overwrites it.
  float* h = (float*)d_out;

  // workspace (~57 MB)
  const size_t yelem = (size_t)N * 128;
  ushort* y0 = (ushort*)d_ws;
  ushort* y1 = y0 + yelem;
  ushort* y2 = y1 + yelem;
  ushort* y3 = y2 + yelem;
  ushort* Wt_in  = y3 + yelem;             // 128*128
  ushort* Wt_out = Wt_in + 128 * 128;      // 128*128
  ushort* Wt_l0  = Wt_out + 128 * 128;     // 128*512
  ushort* Wt_l1  = Wt_l0 + 128 * 512;      // 128*512
  float*  bsum   = (float*)(Wt_l1 + 128 * 512);   // 256
  int*    rowp   = (int*)(bsum + 256);     // N+1
  int*    H      = rowp + (N + 1);         // NB*CSR_B
  uint*   packed = (uint*)(H + MAX_NB * CSR_B);   // E
  ushort* esrc   = (ushort*)(packed + E);  // E

  const int gemmB = (N + 63) / 64;
  const int aggB  = ((N + 63) / 64) * 4;   // node-blocks x 4 chunks
  const int castB = (N * 16 + 255) / 256;

  // ---- CSR build (binned counting sort) ----
  chist_k<<<CSR_B, 256, 0, stream>>>(dst, H, E, NB);
  cscan_k<<<1, 256, 0, stream>>>(H, NB * CSR_B);
  cscatter_k<<<CSR_B, 256, 0, stream>>>(src, dst, H, packed, E, NB);
  fsort_k<<<NB, 256, 0, stream>>>(packed, H, esrc, rowp, N, E, NB);

  // ---- weight prep + x cast (chunked) ----
  prep_k<<<641, 256, 0, stream>>>(w_in, w_out, taps_w, taps_b,
                                  Wt_in, Wt_out, Wt_l0, Wt_l1, bsum);
  cast_f2b<<<castB, 256, 0, stream>>>(x, y1, N);

  // ---- readin: h = lrelu(x@Win+b); y0 = bf16(lrelu(h)) ----
  gemm_mfma<0, 128><<<gemmB, 256, 0, stream>>>(y1, y1, y1, y1, Wt_in, b_in, h, y0, 0, N);

  // ---- 2 residual graph-filter layers (cast fused into GEMM epilogue) ----
  for (int l = 0; l < 2; l++) {
    const ushort* Wt_l = (l == 0) ? Wt_l0 : Wt_l1;
    agg_bf16<<<aggB, 256, 0, stream>>>(y0, y1, rowp, esrc, N);
    agg_bf16<<<aggB, 256, 0, stream>>>(y1, y2, rowp, esrc, N);
    agg_bf16<<<aggB, 256, 0, stream>>>(y2, y3, rowp, esrc, N);
    gemm_mfma<1, 512><<<gemmB, 256, 0, stream>>>(y0, y1, y2, y3, Wt_l, bsum + l * 128,
                                                 h, y0, (l == 0) ? 1 : 0, N);
  }

  // ---- readout: d_out = h @ Wout + bout (reads y0 = bf16(h)) ----
  gemm_mfma<2, 128><<<gemmB, 256, 0, stream>>>(y0, y0, y0, y0, Wt_out, b_out,
                                               (float*)d_out, nullptr, 0, N);
}